// Round 1
// baseline (1083.412 us; speedup 1.0000x reference)
//
#include <hip/hip_runtime.h>

// GCN forward on MI355X.
// Pipeline: CSR build (hist/scan/scatter) -> gemm1 -> spmm1(+b1,relu) -> gemm2 -> spmm2(+b2,log_softmax)
// Workspace layout (~129 MB): support1[NN*128]f, h[NN*128]f, scol[NE]i, sval[NE]f,
//   rowptr[NN+1]i, cnt[NN]i, fillpos[NN]i, partials[1K]i ; support2 aliases support1.

#define NN 100000
#define NE 3200000
#define FIN 512
#define FHID 128
#define FOUT 32

// ---------------- CSR build ----------------
__global__ __launch_bounds__(256) void hist_kernel(const int* __restrict__ erow,
                                                   int* __restrict__ cnt) {
    int e = blockIdx.x * 256 + threadIdx.x;
    if (e < NE) atomicAdd(&cnt[erow[e]], 1);
}

// chunk = 1024 per block; 98 blocks cover 100000
__global__ __launch_bounds__(256) void scan1_kernel(const int* __restrict__ cnt,
                                                    int* __restrict__ rowptr,
                                                    int* __restrict__ partials) {
    __shared__ int s[256];
    int t = threadIdx.x;
    int i0 = blockIdx.x * 1024 + t * 4;
    int v[4];
#pragma unroll
    for (int j = 0; j < 4; ++j) v[j] = (i0 + j < NN) ? cnt[i0 + j] : 0;
    int lsum = v[0] + v[1] + v[2] + v[3];
    s[t] = lsum;
    __syncthreads();
    for (int o = 1; o < 256; o <<= 1) {
        int xv = (t >= o) ? s[t - o] : 0;
        __syncthreads();
        s[t] += xv;
        __syncthreads();
    }
    if (t == 255) partials[blockIdx.x] = s[255];
    int run = s[t] - lsum;  // exclusive prefix of this thread within chunk
#pragma unroll
    for (int j = 0; j < 4; ++j) {
        if (i0 + j < NN) rowptr[i0 + j] = run;
        run += v[j];
    }
}

__global__ void scan2_kernel(int* partials) {
    __shared__ int s[128];
    int t = threadIdx.x;
    int v = (t < 98) ? partials[t] : 0;
    s[t] = v;
    __syncthreads();
    for (int o = 1; o < 128; o <<= 1) {
        int xv = (t >= o) ? s[t - o] : 0;
        __syncthreads();
        s[t] += xv;
        __syncthreads();
    }
    if (t < 98) partials[t] = s[t] - v;  // exclusive
}

__global__ __launch_bounds__(256) void scan3_kernel(int* __restrict__ rowptr,
                                                    const int* __restrict__ partials) {
    int t = threadIdx.x;
    int b = blockIdx.x;
    int add = partials[b];
    int i0 = b * 1024 + t * 4;
#pragma unroll
    for (int j = 0; j < 4; ++j)
        if (i0 + j < NN) rowptr[i0 + j] += add;
    if (b == 0 && t == 0) rowptr[NN] = NE;
}

__global__ __launch_bounds__(256) void scatter_kernel(const int* __restrict__ erow,
                                                      const int* __restrict__ ecol,
                                                      const float* __restrict__ eval,
                                                      const int* __restrict__ rowptr,
                                                      int* __restrict__ fillpos,
                                                      int* __restrict__ scol,
                                                      float* __restrict__ sval) {
    int e = blockIdx.x * 256 + threadIdx.x;
    if (e < NE) {
        int r = erow[e];
        int p = atomicAdd(&fillpos[r], 1);
        int idx = rowptr[r] + p;
        scol[idx] = ecol[e];
        sval[idx] = eval[e];
    }
}

// ---------------- GEMM1: support1 = x @ W1  (NN x 512)@(512 x 128) ----------------
// lane = row (64 rows/block), 4 waves each own a 32-col group.
// W1 operand read through wave-uniform address -> s_load broadcast, so the
// inner loop is 1 ds_read_b32 + 32 v_fma per k per wave (VALU-bound).
__global__ __launch_bounds__(256) void gemm1_kernel(const float* __restrict__ x,
                                                    const float* __restrict__ W1,
                                                    float* __restrict__ out) {
    __shared__ float xs[64][33];  // +1 pad: xs[lane][k] -> bank (lane+k)%32, 2-way (free)
    const int tid = threadIdx.x;
    const int lane = tid & 63;
    const int cg = __builtin_amdgcn_readfirstlane(tid >> 6);  // col group 0..3 (wave-uniform)
    const int row0 = blockIdx.x * 64;
    const int row = row0 + lane;

    float acc[32];
#pragma unroll
    for (int c = 0; c < 32; ++c) acc[c] = 0.f;

    for (int k0 = 0; k0 < FIN; k0 += 32) {
        // stage x[row0..+63][k0..+31]; thread loads 2 float4 (coalesced 128B/row segments)
#pragma unroll
        for (int j = 0; j < 2; ++j) {
            int f = tid * 2 + j;  // 0..511 float4 slots
            int r = f >> 3;       // 0..63
            int kq = f & 7;       // 0..7
            float4 v = make_float4(0.f, 0.f, 0.f, 0.f);
            if (row0 + r < NN)
                v = *(const float4*)(x + (size_t)(row0 + r) * FIN + k0 + kq * 4);
            xs[r][kq * 4 + 0] = v.x;
            xs[r][kq * 4 + 1] = v.y;
            xs[r][kq * 4 + 2] = v.z;
            xs[r][kq * 4 + 3] = v.w;
        }
        __syncthreads();
#pragma unroll 4
        for (int k = 0; k < 32; ++k) {
            float a = xs[lane][k];
            const float* wrow = W1 + (size_t)(k0 + k) * FHID + cg * 32;
#pragma unroll
            for (int c = 0; c < 32; ++c) acc[c] += a * wrow[c];
        }
        __syncthreads();
    }
    if (row < NN) {
        float* op = out + (size_t)row * FHID + cg * 32;
#pragma unroll
        for (int c4 = 0; c4 < 8; ++c4)
            *(float4*)(op + c4 * 4) =
                make_float4(acc[c4 * 4], acc[c4 * 4 + 1], acc[c4 * 4 + 2], acc[c4 * 4 + 3]);
    }
}

// ---------------- SpMM1 + bias + relu: h = relu(A @ support1 + b1) ----------------
// 2 rows per wave: half-wave (32 lanes x float4 = 512B) covers one 128-col row.
__global__ __launch_bounds__(256) void spmm1_kernel(const int* __restrict__ rowptr,
                                                    const int* __restrict__ scol,
                                                    const float* __restrict__ sval,
                                                    const float* __restrict__ dense,
                                                    const float* __restrict__ b1,
                                                    float* __restrict__ h) {
    const int gtid = blockIdx.x * 256 + threadIdx.x;
    const int wid = gtid >> 6;
    const int lane = threadIdx.x & 63;
    const int half = lane >> 5;
    const int sl = lane & 31;
    const int row = wid * 2 + half;  // NN even, grid exact -> always < NN
    const int start = rowptr[row];
    const int cnt = rowptr[row + 1] - start;
    const int maxcnt = max(cnt, __shfl_xor(cnt, 32, 64));
    float4 acc = make_float4(0.f, 0.f, 0.f, 0.f);
    for (int base = 0; base < maxcnt; base += 32) {
        int rem = cnt - base;
        int c = 0;
        float v = 0.f;
        if (sl < rem) {
            c = scol[start + base + sl];
            v = sval[start + base + sl];
        }
        int jn = min(32, maxcnt - base);
        for (int j = 0; j < jn; ++j) {
            int src = half * 32 + j;
            int cj = __shfl(c, src, 64);
            float vj = __shfl(v, src, 64);  // 0 when this half exhausted -> harmless
            float4 s = *(const float4*)(dense + (size_t)cj * FHID + sl * 4);
            acc.x += vj * s.x;
            acc.y += vj * s.y;
            acc.z += vj * s.z;
            acc.w += vj * s.w;
        }
    }
    float4 bb = ((const float4*)b1)[sl];
    acc.x = fmaxf(acc.x + bb.x, 0.f);
    acc.y = fmaxf(acc.y + bb.y, 0.f);
    acc.z = fmaxf(acc.z + bb.z, 0.f);
    acc.w = fmaxf(acc.w + bb.w, 0.f);
    *(float4*)(h + (size_t)row * FHID + sl * 4) = acc;
}

// ---------------- GEMM2: support2 = h @ W2  (NN x 128)@(128 x 32) ----------------
__global__ __launch_bounds__(256) void gemm2_kernel(const float* __restrict__ h,
                                                    const float* __restrict__ W2,
                                                    float* __restrict__ out) {
    __shared__ float hs[64][129];
    const int tid = threadIdx.x;
    const int lane = tid & 63;
    const int cg = __builtin_amdgcn_readfirstlane(tid >> 6);  // cols cg*8..+7
    const int row0 = blockIdx.x * 64;
    const int row = row0 + lane;

    float acc[8];
#pragma unroll
    for (int c = 0; c < 8; ++c) acc[c] = 0.f;

#pragma unroll
    for (int j = 0; j < 8; ++j) {
        int f4 = tid + j * 256;  // 0..2047 float4 slots
        int r = f4 >> 5;         // 0..63
        int kq = f4 & 31;        // 0..31
        float4 v = make_float4(0.f, 0.f, 0.f, 0.f);
        if (row0 + r < NN)
            v = *(const float4*)(h + (size_t)(row0 + r) * FHID + kq * 4);
        hs[r][kq * 4 + 0] = v.x;
        hs[r][kq * 4 + 1] = v.y;
        hs[r][kq * 4 + 2] = v.z;
        hs[r][kq * 4 + 3] = v.w;
    }
    __syncthreads();
#pragma unroll 4
    for (int k = 0; k < FHID; ++k) {
        float a = hs[lane][k];
        const float* wrow = W2 + k * FOUT + cg * 8;
#pragma unroll
        for (int c = 0; c < 8; ++c) acc[c] += a * wrow[c];
    }
    if (row < NN) {
        float* op = out + (size_t)row * FOUT + cg * 8;
        *(float4*)op = make_float4(acc[0], acc[1], acc[2], acc[3]);
        *(float4*)(op + 4) = make_float4(acc[4], acc[5], acc[6], acc[7]);
    }
}

// ------- SpMM2 + bias + log_softmax: out = log_softmax(A @ support2 + b2) -------
// 4 rows per wave: quarter (16 lanes x float2 = 128B) covers one 32-col row.
__global__ __launch_bounds__(256) void spmm2_kernel(const int* __restrict__ rowptr,
                                                    const int* __restrict__ scol,
                                                    const float* __restrict__ sval,
                                                    const float* __restrict__ dense,
                                                    const float* __restrict__ b2,
                                                    float* __restrict__ out) {
    const int gtid = blockIdx.x * 256 + threadIdx.x;
    const int wid = gtid >> 6;
    const int lane = threadIdx.x & 63;
    const int q = lane >> 4;
    const int sl = lane & 15;
    const int row = wid * 4 + q;  // always < NN (grid exact)
    const int start = rowptr[row];
    const int cnt = rowptr[row + 1] - start;
    int m1 = max(cnt, __shfl_xor(cnt, 16, 64));
    const int maxcnt = max(m1, __shfl_xor(m1, 32, 64));
    float2 acc = make_float2(0.f, 0.f);
    for (int base = 0; base < maxcnt; base += 16) {
        int rem = cnt - base;
        int c = 0;
        float v = 0.f;
        if (sl < rem) {
            c = scol[start + base + sl];
            v = sval[start + base + sl];
        }
        int jn = min(16, maxcnt - base);
        for (int j = 0; j < jn; ++j) {
            int src = q * 16 + j;
            int cj = __shfl(c, src, 64);
            float vj = __shfl(v, src, 64);
            float2 s = *(const float2*)(dense + (size_t)cj * FOUT + sl * 2);
            acc.x += vj * s.x;
            acc.y += vj * s.y;
        }
    }
    float2 bb = ((const float2*)b2)[sl];
    acc.x += bb.x;
    acc.y += bb.y;
    // log_softmax over the row's 32 cols (16 lanes x 2)
    float m = fmaxf(acc.x, acc.y);
#pragma unroll
    for (int mask = 8; mask >= 1; mask >>= 1) m = fmaxf(m, __shfl_xor(m, mask, 64));
    float ssum = expf(acc.x - m) + expf(acc.y - m);
#pragma unroll
    for (int mask = 8; mask >= 1; mask >>= 1) ssum += __shfl_xor(ssum, mask, 64);
    float lse = m + logf(ssum);
    *(float2*)(out + (size_t)row * FOUT + sl * 2) = make_float2(acc.x - lse, acc.y - lse);
}

extern "C" void kernel_launch(void* const* d_in, const int* in_sizes, int n_in,
                              void* d_out, int out_size, void* d_ws, size_t ws_size,
                              hipStream_t stream) {
    const float* x = (const float*)d_in[0];
    const int* erow = (const int*)d_in[1];
    const int* ecol = (const int*)d_in[2];
    const float* eval = (const float*)d_in[3];
    const float* W1 = (const float*)d_in[4];
    const float* b1 = (const float*)d_in[5];
    const float* W2 = (const float*)d_in[6];
    const float* b2 = (const float*)d_in[7];
    float* out = (float*)d_out;

    char* ws = (char*)d_ws;
    size_t off = 0;
    auto walloc = [&](size_t bytes) -> void* {
        void* p = ws + off;
        off = (off + bytes + 255) & ~(size_t)255;
        return p;
    };
    float* support1 = (float*)walloc((size_t)NN * FHID * 4);
    float* h = (float*)walloc((size_t)NN * FHID * 4);
    int* scol = (int*)walloc((size_t)NE * 4);
    float* sval = (float*)walloc((size_t)NE * 4);
    int* rowptr = (int*)walloc((size_t)(NN + 1) * 4);
    int* cnt = (int*)walloc((size_t)NN * 4);
    int* fillpos = (int*)walloc((size_t)NN * 4);
    int* partials = (int*)walloc(4096);
    float* support2 = support1;  // support1 dead after spmm1; safe alias

    hipMemsetAsync(cnt, 0, (size_t)NN * 4, stream);
    hipMemsetAsync(fillpos, 0, (size_t)NN * 4, stream);

    hist_kernel<<<(NE + 255) / 256, 256, 0, stream>>>(erow, cnt);
    scan1_kernel<<<98, 256, 0, stream>>>(cnt, rowptr, partials);
    scan2_kernel<<<1, 128, 0, stream>>>(partials);
    scan3_kernel<<<98, 256, 0, stream>>>(rowptr, partials);
    scatter_kernel<<<(NE + 255) / 256, 256, 0, stream>>>(erow, ecol, eval, rowptr, fillpos,
                                                         scol, sval);

    gemm1_kernel<<<(NN + 63) / 64, 256, 0, stream>>>(x, W1, support1);
    spmm1_kernel<<<NN / 8, 256, 0, stream>>>(rowptr, scol, sval, support1, b1, h);
    gemm2_kernel<<<(NN + 63) / 64, 256, 0, stream>>>(h, W2, support2);
    spmm2_kernel<<<NN / 16, 256, 0, stream>>>(rowptr, scol, sval, support2, b2, out);
}

// Round 2
// 939.489 us; speedup vs baseline: 1.1532x; 1.1532x over previous
//
#include <hip/hip_runtime.h>

// GCN forward on MI355X — bf16 intermediate pipeline.
// CSR build (hist/scan/scatter, packed int2 edges) -> gemm1 (MFMA bf16) ->
// spmm1(+b1,relu, bf16 gather) -> gemm2 (VALU, bf16 in/out) -> spmm2(+b2,log_softmax fp32 out)

#define NN 100000
#define NE 3200000
#define FIN 512
#define FHID 128
#define FOUT 32

typedef __attribute__((ext_vector_type(8))) short bf16x8;
typedef __attribute__((ext_vector_type(4))) float f32x4;

static __device__ __forceinline__ unsigned short f2bf(float f) {
    unsigned u = __float_as_uint(f);
    unsigned r = (u + 0x7FFFu + ((u >> 16) & 1u)) >> 16;  // RTN-even
    return (unsigned short)r;
}
static __device__ __forceinline__ float bf2f(unsigned short u) {
    return __uint_as_float(((unsigned)u) << 16);
}

// ---------------- CSR build ----------------
__global__ __launch_bounds__(256) void hist_kernel(const int* __restrict__ erow,
                                                   int* __restrict__ cnt) {
    int e = blockIdx.x * 256 + threadIdx.x;
    if (e < NE) atomicAdd(&cnt[erow[e]], 1);
}

__global__ __launch_bounds__(256) void scan1_kernel(const int* __restrict__ cnt,
                                                    int* __restrict__ rowptr,
                                                    int* __restrict__ partials) {
    __shared__ int s[256];
    int t = threadIdx.x;
    int i0 = blockIdx.x * 1024 + t * 4;
    int v[4];
#pragma unroll
    for (int j = 0; j < 4; ++j) v[j] = (i0 + j < NN) ? cnt[i0 + j] : 0;
    int lsum = v[0] + v[1] + v[2] + v[3];
    s[t] = lsum;
    __syncthreads();
    for (int o = 1; o < 256; o <<= 1) {
        int xv = (t >= o) ? s[t - o] : 0;
        __syncthreads();
        s[t] += xv;
        __syncthreads();
    }
    if (t == 255) partials[blockIdx.x] = s[255];
    int run = s[t] - lsum;
#pragma unroll
    for (int j = 0; j < 4; ++j) {
        if (i0 + j < NN) rowptr[i0 + j] = run;
        run += v[j];
    }
}

__global__ void scan2_kernel(int* partials) {
    __shared__ int s[128];
    int t = threadIdx.x;
    int v = (t < 98) ? partials[t] : 0;
    s[t] = v;
    __syncthreads();
    for (int o = 1; o < 128; o <<= 1) {
        int xv = (t >= o) ? s[t - o] : 0;
        __syncthreads();
        s[t] += xv;
        __syncthreads();
    }
    if (t < 98) partials[t] = s[t] - v;
}

__global__ __launch_bounds__(256) void scan3_kernel(int* __restrict__ rowptr,
                                                    int* __restrict__ fillpos,
                                                    const int* __restrict__ partials) {
    int t = threadIdx.x;
    int b = blockIdx.x;
    int add = partials[b];
    int i0 = b * 1024 + t * 4;
#pragma unroll
    for (int j = 0; j < 4; ++j)
        if (i0 + j < NN) {
            int v = rowptr[i0 + j] + add;
            rowptr[i0 + j] = v;
            fillpos[i0 + j] = v;
        }
    if (b == 0 && t == 0) rowptr[NN] = NE;
}

__global__ __launch_bounds__(256) void scatter_kernel(const int* __restrict__ erow,
                                                      const int* __restrict__ ecol,
                                                      const float* __restrict__ eval,
                                                      int* __restrict__ fillpos,
                                                      int2* __restrict__ epack) {
    int e = blockIdx.x * 256 + threadIdx.x;
    if (e < NE) {
        int r = erow[e];
        int idx = atomicAdd(&fillpos[r], 1);
        epack[idx] = make_int2(ecol[e], __float_as_int(eval[e]));
    }
}

// ---------------- W1 prep: fp32 [512][128] -> bf16 transposed [128][512] ----------------
__global__ __launch_bounds__(256) void prep_w1(const float* __restrict__ W1,
                                               unsigned short* __restrict__ W1t) {
    int t = blockIdx.x * 256 + threadIdx.x;  // 65536 total
    int n = t & 127;
    int k = t >> 7;
    W1t[n * 512 + k] = f2bf(W1[k * 128 + n]);
}

// ---------------- GEMM1 (MFMA): support1(bf16) = x(f32) @ W1 ----------------
// Block: 256 thr = 4 waves, tile 128Mx128N, K-loop 16 steps of BK=32.
// A staged in LDS in MFMA-fragment order (conflict-free ds_read_b128);
// B frags loaded directly from W1t (L2-resident). mfma_f32_16x16x32_bf16.
__global__ __launch_bounds__(256) void gemm1_mfma(const float* __restrict__ x,
                                                  const unsigned short* __restrict__ W1t,
                                                  unsigned short* __restrict__ out) {
    __shared__ __align__(16) unsigned short As[128 * 32];  // 8 KB, fragment order
    const int tid = threadIdx.x;
    const int lane = tid & 63;
    const int w = __builtin_amdgcn_readfirstlane(tid >> 6);  // wave 0..3 -> cols w*32..+31
    const int quad = lane >> 4;
    const int m = lane & 15;
    const int row0 = blockIdx.x * 128;

    f32x4 acc[8][2];
#pragma unroll
    for (int mt = 0; mt < 8; ++mt)
#pragma unroll
        for (int nt = 0; nt < 2; ++nt) acc[mt][nt] = (f32x4){0.f, 0.f, 0.f, 0.f};

    // staging slots: f = tid + s*256 ; r = f>>3 (0..127), kq = f&7 (float4 within BK=32)
    int srow[4], skq[4];
    const float* sptr[4];
#pragma unroll
    for (int s = 0; s < 4; ++s) {
        int f = tid + s * 256;
        srow[s] = f >> 3;
        skq[s] = f & 7;
        sptr[s] = x + (size_t)(row0 + srow[s]) * FIN + skq[s] * 4;
    }
    float4 ld[4];
#pragma unroll
    for (int s = 0; s < 4; ++s)
        ld[s] = (row0 + srow[s] < NN) ? *(const float4*)sptr[s]
                                      : make_float4(0.f, 0.f, 0.f, 0.f);

    for (int ks = 0; ks < 16; ++ks) {
        __syncthreads();  // previous iteration's frag reads done
#pragma unroll
        for (int s = 0; s < 4; ++s) {
            int r = srow[s], kq = skq[s];
            int mt = r >> 4, mm = r & 15;
            int off = mt * 512 + (kq >> 1) * 128 + mm * 8 + (kq & 1) * 4;
            ushort4 p;
            p.x = f2bf(ld[s].x);
            p.y = f2bf(ld[s].y);
            p.z = f2bf(ld[s].z);
            p.w = f2bf(ld[s].w);
            *(ushort4*)&As[off] = p;
        }
        __syncthreads();
        if (ks < 15) {
#pragma unroll
            for (int s = 0; s < 4; ++s)
                ld[s] = (row0 + srow[s] < NN)
                            ? *(const float4*)(sptr[s] + (ks + 1) * 32)
                            : make_float4(0.f, 0.f, 0.f, 0.f);
        }
        bf16x8 bfr[2];
#pragma unroll
        for (int nt = 0; nt < 2; ++nt) {
            int n = (w * 2 + nt) * 16 + m;
            bfr[nt] = *(const bf16x8*)(W1t + (size_t)n * 512 + ks * 32 + quad * 8);
        }
#pragma unroll
        for (int mt = 0; mt < 8; ++mt) {
            bf16x8 af = *(const bf16x8*)&As[mt * 512 + quad * 128 + m * 8];
            acc[mt][0] = __builtin_amdgcn_mfma_f32_16x16x32_bf16(af, bfr[0], acc[mt][0], 0, 0, 0);
            acc[mt][1] = __builtin_amdgcn_mfma_f32_16x16x32_bf16(af, bfr[1], acc[mt][1], 0, 0, 0);
        }
    }
    // C/D layout: col = lane&15, row = quad*4 + reg
#pragma unroll
    for (int mt = 0; mt < 8; ++mt)
#pragma unroll
        for (int nt = 0; nt < 2; ++nt) {
            int col = (w * 2 + nt) * 16 + m;
#pragma unroll
            for (int r = 0; r < 4; ++r) {
                int row = row0 + mt * 16 + quad * 4 + r;
                if (row < NN) out[(size_t)row * FHID + col] = f2bf(acc[mt][nt][r]);
            }
        }
}

// ---------------- SpMM1 + bias + relu: h(bf16) = relu(A @ support1 + b1) ----------------
// 2 rows/wave: half-wave (32 lanes x 8B bf16x4) covers one 256B row.
__global__ __launch_bounds__(256) void spmm1_kernel(const int* __restrict__ rowptr,
                                                    const int2* __restrict__ epack,
                                                    const unsigned short* __restrict__ dense,
                                                    const float* __restrict__ b1,
                                                    unsigned short* __restrict__ h) {
    const int gtid = blockIdx.x * 256 + threadIdx.x;
    const int wid = gtid >> 6;
    const int lane = threadIdx.x & 63;
    const int half = lane >> 5;
    const int sl = lane & 31;
    const int row = wid * 2 + half;
    const int start = rowptr[row];
    const int cnt = rowptr[row + 1] - start;
    const int maxcnt = max(cnt, __shfl_xor(cnt, 32, 64));
    float4 acc = make_float4(0.f, 0.f, 0.f, 0.f);
    for (int base = 0; base < maxcnt; base += 32) {
        int rem = cnt - base;
        int2 p = make_int2(0, 0);
        if (sl < rem) p = epack[start + base + sl];
        int jn = min(32, maxcnt - base);
        for (int j = 0; j < jn; ++j) {
            int src = half * 32 + j;
            int cj = __shfl(p.x, src, 64);
            float vj = __shfl(__int_as_float(p.y), src, 64);
            uint2 d = *(const uint2*)(dense + (size_t)cj * FHID + sl * 4);
            acc.x += vj * __uint_as_float(d.x << 16);
            acc.y += vj * __uint_as_float(d.x & 0xffff0000u);
            acc.z += vj * __uint_as_float(d.y << 16);
            acc.w += vj * __uint_as_float(d.y & 0xffff0000u);
        }
    }
    float4 bb = ((const float4*)b1)[sl];
    ushort4 o;
    o.x = f2bf(fmaxf(acc.x + bb.x, 0.f));
    o.y = f2bf(fmaxf(acc.y + bb.y, 0.f));
    o.z = f2bf(fmaxf(acc.z + bb.z, 0.f));
    o.w = f2bf(fmaxf(acc.w + bb.w, 0.f));
    *(ushort4*)(h + (size_t)row * FHID + sl * 4) = o;
}

// ---------------- GEMM2: support2(bf16) = h(bf16) @ W2(f32) ----------------
__global__ __launch_bounds__(256) void gemm2_kernel(const unsigned short* __restrict__ h,
                                                    const float* __restrict__ W2,
                                                    unsigned short* __restrict__ out) {
    __shared__ float hs[64][129];
    const int tid = threadIdx.x;
    const int lane = tid & 63;
    const int cg = __builtin_amdgcn_readfirstlane(tid >> 6);  // cols cg*8..+7
    const int row0 = blockIdx.x * 64;
    const int row = row0 + lane;

    float acc[8];
#pragma unroll
    for (int c = 0; c < 8; ++c) acc[c] = 0.f;

#pragma unroll
    for (int j = 0; j < 8; ++j) {
        int f4 = tid + j * 256;  // 2048 slots of 4 bf16
        int r = f4 >> 5;
        int kq = f4 & 31;
        ushort4 v = make_ushort4(0, 0, 0, 0);
        if (row0 + r < NN) v = *(const ushort4*)(h + (size_t)(row0 + r) * FHID + kq * 4);
        hs[r][kq * 4 + 0] = bf2f(v.x);
        hs[r][kq * 4 + 1] = bf2f(v.y);
        hs[r][kq * 4 + 2] = bf2f(v.z);
        hs[r][kq * 4 + 3] = bf2f(v.w);
    }
    __syncthreads();
#pragma unroll 4
    for (int k = 0; k < FHID; ++k) {
        float a = hs[lane][k];
        const float* wrow = W2 + k * FOUT + cg * 8;
#pragma unroll
        for (int c = 0; c < 8; ++c) acc[c] += a * wrow[c];
    }
    if (row < NN) {
        uint4 st;
        st.x = (unsigned)f2bf(acc[0]) | ((unsigned)f2bf(acc[1]) << 16);
        st.y = (unsigned)f2bf(acc[2]) | ((unsigned)f2bf(acc[3]) << 16);
        st.z = (unsigned)f2bf(acc[4]) | ((unsigned)f2bf(acc[5]) << 16);
        st.w = (unsigned)f2bf(acc[6]) | ((unsigned)f2bf(acc[7]) << 16);
        *(uint4*)(out + (size_t)row * FOUT + cg * 8) = st;
    }
}

// ------- SpMM2 + bias + log_softmax (fp32 out) -------
// 4 rows/wave: quarter (16 lanes x 4B bf16x2) covers one 64B row.
__global__ __launch_bounds__(256) void spmm2_kernel(const int* __restrict__ rowptr,
                                                    const int2* __restrict__ epack,
                                                    const unsigned short* __restrict__ dense,
                                                    const float* __restrict__ b2,
                                                    float* __restrict__ out) {
    const int gtid = blockIdx.x * 256 + threadIdx.x;
    const int wid = gtid >> 6;
    const int lane = threadIdx.x & 63;
    const int q = lane >> 4;
    const int sl = lane & 15;
    const int row = wid * 4 + q;
    const int start = rowptr[row];
    const int cnt = rowptr[row + 1] - start;
    int m1 = max(cnt, __shfl_xor(cnt, 16, 64));
    const int maxcnt = max(m1, __shfl_xor(m1, 32, 64));
    float2 acc = make_float2(0.f, 0.f);
    for (int base = 0; base < maxcnt; base += 16) {
        int rem = cnt - base;
        int2 p = make_int2(0, 0);
        if (sl < rem) p = epack[start + base + sl];
        int jn = min(16, maxcnt - base);
        for (int j = 0; j < jn; ++j) {
            int src = q * 16 + j;
            int cj = __shfl(p.x, src, 64);
            float vj = __shfl(__int_as_float(p.y), src, 64);
            unsigned d = *(const unsigned*)(dense + (size_t)cj * FOUT + sl * 2);
            acc.x += vj * __uint_as_float(d << 16);
            acc.y += vj * __uint_as_float(d & 0xffff0000u);
        }
    }
    float2 bb = ((const float2*)b2)[sl];
    acc.x += bb.x;
    acc.y += bb.y;
    float m = fmaxf(acc.x, acc.y);
#pragma unroll
    for (int mask = 8; mask >= 1; mask >>= 1) m = fmaxf(m, __shfl_xor(m, mask, 64));
    float ssum = expf(acc.x - m) + expf(acc.y - m);
#pragma unroll
    for (int mask = 8; mask >= 1; mask >>= 1) ssum += __shfl_xor(ssum, mask, 64);
    float lse = m + logf(ssum);
    *(float2*)(out + (size_t)row * FOUT + sl * 2) = make_float2(acc.x - lse, acc.y - lse);
}

extern "C" void kernel_launch(void* const* d_in, const int* in_sizes, int n_in,
                              void* d_out, int out_size, void* d_ws, size_t ws_size,
                              hipStream_t stream) {
    const float* x = (const float*)d_in[0];
    const int* erow = (const int*)d_in[1];
    const int* ecol = (const int*)d_in[2];
    const float* eval = (const float*)d_in[3];
    const float* W1 = (const float*)d_in[4];
    const float* b1 = (const float*)d_in[5];
    const float* W2 = (const float*)d_in[6];
    const float* b2 = (const float*)d_in[7];
    float* out = (float*)d_out;

    char* ws = (char*)d_ws;
    size_t off = 0;
    auto walloc = [&](size_t bytes) -> void* {
        void* p = ws + off;
        off = (off + bytes + 255) & ~(size_t)255;
        return p;
    };
    unsigned short* support1 = (unsigned short*)walloc((size_t)NN * FHID * 2);  // bf16
    unsigned short* h = (unsigned short*)walloc((size_t)NN * FHID * 2);         // bf16
    int2* epack = (int2*)walloc((size_t)NE * 8);
    int* rowptr = (int*)walloc((size_t)(NN + 1) * 4);
    int* cnt = (int*)walloc((size_t)NN * 4);
    int* fillpos = (int*)walloc((size_t)NN * 4);
    int* partials = (int*)walloc(4096);
    unsigned short* W1t = (unsigned short*)walloc((size_t)FHID * FIN * 2);
    unsigned short* support2 = support1;  // support1 dead after spmm1

    hipMemsetAsync(cnt, 0, (size_t)NN * 4, stream);

    prep_w1<<<256, 256, 0, stream>>>(W1, W1t);
    hist_kernel<<<(NE + 255) / 256, 256, 0, stream>>>(erow, cnt);
    scan1_kernel<<<98, 256, 0, stream>>>(cnt, rowptr, partials);
    scan2_kernel<<<1, 128, 0, stream>>>(partials);
    scan3_kernel<<<98, 256, 0, stream>>>(rowptr, fillpos, partials);
    scatter_kernel<<<(NE + 255) / 256, 256, 0, stream>>>(erow, ecol, eval, fillpos, epack);

    gemm1_mfma<<<(NN + 127) / 128, 256, 0, stream>>>(x, W1t, support1);
    spmm1_kernel<<<NN / 8, 256, 0, stream>>>(rowptr, epack, support1, b1, h);
    gemm2_kernel<<<(NN + 63) / 64, 256, 0, stream>>>(h, W2, support2);
    spmm2_kernel<<<NN / 16, 256, 0, stream>>>(rowptr, epack, support2, b2, out);
}